// Round 18
// baseline (121.406 us; speedup 1.0000x reference)
//
#include <hip/hip_runtime.h>
#include <hip/hip_bf16.h>
#include <math.h>

// Problem constants
#define Bz    4
#define Cch   192
#define Nn    4096
#define BN    16384      // Bz*Nn
#define Ecnt  262144     // Bz*Nn*16
#define COUT  384
#define CAP   64         // max degree capacity (random 262144->16384 bins: max ~34)
#define MSTR  200        // Ms/Xs row stride in shorts (400 B)

typedef __attribute__((ext_vector_type(8))) short short8;
typedef __attribute__((ext_vector_type(4))) float floatx4;

__device__ __forceinline__ float b2f(unsigned short u) {
    union { unsigned int i; float f; } z; z.i = ((unsigned int)u) << 16; return z.f;
}
__device__ __forceinline__ unsigned short f2b(float f) {
    __hip_bfloat16 h = __float2bfloat16(f);
    return *(unsigned short*)&h;
}

#define RED8(mm, FLD) do {                                                    \
    float a_ = fmaxf(fmaxf(b2f(v[0].FLD), b2f(v[1].FLD)),                     \
                     fmaxf(b2f(v[2].FLD), b2f(v[3].FLD)));                    \
    float b_ = fmaxf(fmaxf(b2f(v[4].FLD), b2f(v[5].FLD)),                     \
                     fmaxf(b2f(v[6].FLD), b2f(v[7].FLD)));                    \
    mm = fmaxf(mm, fmaxf(a_, b_)); } while (0)

#define RED16(mm, FLD) do {                                                   \
    float a_ = fmaxf(fmaxf(fmaxf(b2f(v[0].FLD), b2f(v[1].FLD)),               \
                           fmaxf(b2f(v[2].FLD), b2f(v[3].FLD))),              \
                     fmaxf(fmaxf(b2f(v[4].FLD), b2f(v[5].FLD)),               \
                           fmaxf(b2f(v[6].FLD), b2f(v[7].FLD))));             \
    float b_ = fmaxf(fmaxf(fmaxf(b2f(v[8].FLD), b2f(v[9].FLD)),               \
                           fmaxf(b2f(v[10].FLD), b2f(v[11].FLD))),            \
                     fmaxf(fmaxf(b2f(v[12].FLD), b2f(v[13].FLD)),             \
                           fmaxf(b2f(v[14].FLD), b2f(v[15].FLD))));           \
    mm = fmaxf(mm, fmaxf(a_, b_)); } while (0)

// ---------------------------------------------------------------------------
// Combo kernel (R18): prep + fill fused into one dispatch. deg is zeroed by a
// prior hipMemsetAsync, which removes the only cross-stage dependency, so the
// fill blocks' atomic latency hides under the transpose blocks' BW phase.
//  [0,3072):    transpose x -> xb bf16 (R2-proven tile)
//  [3072,3360): W -> Wxa=bf16(Wx-Wa), Wa=bf16(Wa)
//  [3360,3872): fill — degree count + slot table, 2 edges/thread
// Algebra: out = Wx·x + Wa·(M-x) = (Wx-Wa)·x + Wa·M', M' = (d>0 ? max : x).
template <int IS64>
__global__ __launch_bounds__(256) void combo_kernel(
    const float* __restrict__ x, const float* __restrict__ W,
    const int* __restrict__ ew, __hip_bfloat16* __restrict__ xb,
    __hip_bfloat16* __restrict__ Wxa, __hip_bfloat16* __restrict__ Wa,
    int* __restrict__ deg, int* __restrict__ slots) {
    int bid = blockIdx.x;
    if (bid < 3072) {
        __shared__ float tile[32][33];
        int b = bid / 768;
        int r = bid - b * 768;
        int c0 = (r >> 7) * 32;         // 6 c-tiles
        int n0 = (r & 127) * 32;        // 128 n-tiles
        int tx = threadIdx.x & 31, ty = threadIdx.x >> 5;
        for (int i = ty; i < 32; i += 8)
            tile[i][tx] = x[((size_t)(b * Cch + c0 + i)) * Nn + n0 + tx];
        __syncthreads();
        for (int i = ty; i < 32; i += 8)
            xb[((size_t)(b * Nn + n0 + i)) * Cch + c0 + tx] =
                __float2bfloat16(tile[tx][i]);
    } else if (bid < 3360) {
        int i = (bid - 3072) * 256 + threadIdx.x;   // exactly COUT*Cch = 73728
        int o = i / Cch, c = i - o * Cch;
        float wx = W[o * 2 * Cch + 2 * c];
        float wa = W[o * 2 * Cch + 2 * c + 1];
        Wxa[i] = __float2bfloat16(wx - wa);          // fp32 difference, one rounding
        Wa[i]  = __float2bfloat16(wa);
    } else {
        int t = (bid - 3360) * 256 + threadIdx.x;   // [0, Ecnt/2), 2 edges/thread
        int d0, d1, s0, s1;
        if (IS64) {     // int64: dst e -> word 2e; src e -> word 2*Ecnt + 2e
            int4 dv = *(const int4*)&ew[4 * t];
            int4 sv = *(const int4*)&ew[2 * Ecnt + 4 * t];
            d0 = dv.x; d1 = dv.z; s0 = sv.x; s1 = sv.z;
        } else {        // int32
            int2 dv = *(const int2*)&ew[2 * t];
            int2 sv = *(const int2*)&ew[Ecnt + 2 * t];
            d0 = dv.x; d1 = dv.y; s0 = sv.x; s1 = sv.y;
        }
        int p0 = atomicAdd(&deg[d0], 1); if (p0 < CAP) slots[(d0 << 6) + p0] = s0;
        int p1 = atomicAdd(&deg[d1], 1); if (p1 < CAP) slots[(d1 << 6) + p1] = s1;
    }
}

// ---------------------------------------------------------------------------
// Fused gather+GEMM (R17-measured, unchanged). Block = 32 nodes x 384 outs,
// 512 threads (8 waves), 512 blocks.
//  - slots[] loaded unconditionally -> deg/slots/x-row chains issue in parallel.
//  - 16-deep gather batches (32 result VGPRs in flight under (512,4)).
//  - Phase B: W fragments from global (L2-resident), 1-step prefetch,
//    no K-loop barriers. Accum order: seg0 s=0..5 then seg1 (same absmax).
#define MFMA6()                                                                \
    acc00 = __builtin_amdgcn_mfma_f32_16x16x32_bf16(b0, af0, acc00, 0, 0, 0);  \
    acc10 = __builtin_amdgcn_mfma_f32_16x16x32_bf16(b0, af1, acc10, 0, 0, 0);  \
    acc01 = __builtin_amdgcn_mfma_f32_16x16x32_bf16(b1, af0, acc01, 0, 0, 0);  \
    acc11 = __builtin_amdgcn_mfma_f32_16x16x32_bf16(b1, af1, acc11, 0, 0, 0);  \
    acc02 = __builtin_amdgcn_mfma_f32_16x16x32_bf16(b2, af0, acc02, 0, 0, 0);  \
    acc12 = __builtin_amdgcn_mfma_f32_16x16x32_bf16(b2, af1, acc12, 0, 0, 0)

__global__ __launch_bounds__(512, 4) void p2_kernel(
    const int* __restrict__ deg, const int* __restrict__ slots,
    const __hip_bfloat16* __restrict__ xb,
    const __hip_bfloat16* __restrict__ Wxa, const __hip_bfloat16* __restrict__ Wa,
    const float* __restrict__ bias, float* __restrict__ out)
{
    __shared__ __align__(16) unsigned short Xs[32 * MSTR];
    __shared__ __align__(16) unsigned short Ms[32 * MSTR];
    int tid = threadIdx.x, bid = blockIdx.x;
    int lane = tid & 63, wave = tid >> 6;    // wave 0..7
    int quad = lane >> 4, lrow = lane & 15;
    int node0 = bid * 32;
    const unsigned short* xbu = (const unsigned short*)xb;
    int act = lane < 48;
    int cb = lane * 4;

    // ---- Phase A prologue: all 4 nodes' deg/slots/x-row issued in parallel ----
    int dd[4], nbrv[4];
    ushort4 xv[4];
#pragma unroll
    for (int q = 0; q < 4; q++) {
        int node = node0 + wave * 4 + q;
        dd[q]   = deg[node];                      // chain 1
        nbrv[q] = slots[(node << 6) + lane];      // chain 2 (independent of deg)
        xv[q]   = act ? *(const ushort4*)&xbu[node * Cch + cb]
                      : (ushort4){0, 0, 0, 0};    // chain 3
    }

    // ---- Phase A: gather M', 4 nodes per wave, 16-deep load batches ----
#pragma unroll
    for (int q = 0; q < 4; q++) {
        int nl = wave * 4 + q;
        int d = dd[q]; if (d > CAP) d = CAP;
        d = __builtin_amdgcn_readfirstlane(d);    // wave-uniform loop bound
        int nbrval = nbrv[q];
        float m0 = -INFINITY, m1 = -INFINITY, m2 = -INFINITY, m3 = -INFINITY;
        int k = 0;
        for (; k + 16 <= d; k += 16) {
            int s[16];
#pragma unroll
            for (int u = 0; u < 16; u++) s[u] = __builtin_amdgcn_readlane(nbrval, k + u);
            if (act) {
                ushort4 v[16];
#pragma unroll
                for (int u = 0; u < 16; u++) v[u] = *(const ushort4*)&xbu[s[u] * Cch + cb];
                RED16(m0, x); RED16(m1, y); RED16(m2, z); RED16(m3, w);
            }
        }
        for (; k + 8 <= d; k += 8) {
            int s[8];
#pragma unroll
            for (int u = 0; u < 8; u++) s[u] = __builtin_amdgcn_readlane(nbrval, k + u);
            if (act) {
                ushort4 v[8];
#pragma unroll
                for (int u = 0; u < 8; u++) v[u] = *(const ushort4*)&xbu[s[u] * Cch + cb];
                RED8(m0, x); RED8(m1, y); RED8(m2, z); RED8(m3, w);
            }
        }
        if (k + 4 <= d) {
            int s0 = __builtin_amdgcn_readlane(nbrval, k);
            int s1 = __builtin_amdgcn_readlane(nbrval, k + 1);
            int s2 = __builtin_amdgcn_readlane(nbrval, k + 2);
            int s3 = __builtin_amdgcn_readlane(nbrval, k + 3);
            if (act) {
                ushort4 v0 = *(const ushort4*)&xbu[s0 * Cch + cb];
                ushort4 v1 = *(const ushort4*)&xbu[s1 * Cch + cb];
                ushort4 v2 = *(const ushort4*)&xbu[s2 * Cch + cb];
                ushort4 v3 = *(const ushort4*)&xbu[s3 * Cch + cb];
                m0 = fmaxf(m0, fmaxf(fmaxf(b2f(v0.x), b2f(v1.x)), fmaxf(b2f(v2.x), b2f(v3.x))));
                m1 = fmaxf(m1, fmaxf(fmaxf(b2f(v0.y), b2f(v1.y)), fmaxf(b2f(v2.y), b2f(v3.y))));
                m2 = fmaxf(m2, fmaxf(fmaxf(b2f(v0.z), b2f(v1.z)), fmaxf(b2f(v2.z), b2f(v3.z))));
                m3 = fmaxf(m3, fmaxf(fmaxf(b2f(v0.w), b2f(v1.w)), fmaxf(b2f(v2.w), b2f(v3.w))));
            }
            k += 4;
        }
        for (; k < d; k++) {
            int s = __builtin_amdgcn_readlane(nbrval, k);
            if (act) {
                ushort4 v = *(const ushort4*)&xbu[s * Cch + cb];
                m0 = fmaxf(m0, b2f(v.x)); m1 = fmaxf(m1, b2f(v.y));
                m2 = fmaxf(m2, b2f(v.z)); m3 = fmaxf(m3, b2f(v.w));
            }
        }
        if (act) {
            *(ushort4*)&Xs[nl * MSTR + cb] = xv[q];
            ushort4 o4;
            if (d > 0) {                      // wave-uniform branch
                o4.x = f2b(m0); o4.y = f2b(m1); o4.z = f2b(m2); o4.w = f2b(m3);
            } else {                          // empty segment: M' = x (cancels)
                o4 = xv[q];
            }
            *(ushort4*)&Ms[nl * MSTR + cb] = o4;
        }
    }
    __syncthreads();

    // ---- Phase B: K-loop, no barriers, 1-step W prefetch ----
    floatx4 acc00 = {}, acc01 = {}, acc02 = {}, acc10 = {}, acc11 = {}, acc12 = {};
    const unsigned short* Wx16 = (const unsigned short*)Wxa;
    const unsigned short* Wa16 = (const unsigned short*)Wa;
    size_t w0 = (size_t)(wave * 48 +  0 + lrow) * Cch;
    size_t w1 = (size_t)(wave * 48 + 16 + lrow) * Cch;
    size_t w2 = (size_t)(wave * 48 + 32 + lrow) * Cch;
    int kq = quad * 8;

    short8 b0 = *(const short8*)&Wx16[w0 + kq];
    short8 b1 = *(const short8*)&Wx16[w1 + kq];
    short8 b2 = *(const short8*)&Wx16[w2 + kq];
#pragma unroll
    for (int s = 0; s < 12; s++) {
        short8 n0, n1, n2;
        if (s < 11) {
            int sn = s + 1;
            const unsigned short* Wn = (sn >= 6) ? Wa16 : Wx16;
            int kkn = ((sn >= 6) ? sn - 6 : sn) * 32 + kq;
            n0 = *(const short8*)&Wn[w0 + kkn];
            n1 = *(const short8*)&Wn[w1 + kkn];
            n2 = *(const short8*)&Wn[w2 + kkn];
        }
        int kk = ((s >= 6) ? s - 6 : s) * 32 + kq;
        const unsigned short* Ar = (s >= 6) ? Ms : Xs;
        short8 af0 = *(const short8*)&Ar[lrow * MSTR + kk];
        short8 af1 = *(const short8*)&Ar[(16 + lrow) * MSTR + kk];
        MFMA6();
        if (s < 11) { b0 = n0; b1 = n1; b2 = n2; }
    }

    // ---- Epilogue. D layout: col(lane&15)=node, row(quad*4+r)=o ----
    floatx4 accs[2][3] = {{acc00, acc01, acc02}, {acc10, acc11, acc12}};
#pragma unroll
    for (int i = 0; i < 2; i++) {
        int node = node0 + i * 16 + lrow;
        int b = node >> 12, n = node & 4095;
#pragma unroll
        for (int j = 0; j < 3; j++) {
            int ob = wave * 48 + j * 16 + quad * 4;
#pragma unroll
            for (int r = 0; r < 4; r++) {
                int o = ob + r;
                float v = accs[i][j][r] + bias[o];
                out[((size_t)(b * COUT + o)) * Nn + n] = fmaxf(v, 0.0f);
            }
        }
    }
}

// ---------------------------------------------------------------------------
extern "C" void kernel_launch(void* const* d_in, const int* in_sizes, int n_in,
                              void* d_out, int out_size, void* d_ws, size_t ws_size,
                              hipStream_t stream) {
    const float* x    = (const float*)d_in[0];
    const int*   ew   = (const int*)d_in[1];
    const float* W    = (const float*)d_in[2];
    const float* bias = (const float*)d_in[3];
    float* out        = (float*)d_out;

    char* ws = (char*)d_ws;
    __hip_bfloat16* xb   = (__hip_bfloat16*)ws;                       // 6291456 B
    __hip_bfloat16* Wxa  = (__hip_bfloat16*)(ws + 12582912);          // 147456 B
    __hip_bfloat16* Wa   = (__hip_bfloat16*)(ws + 12730368);          // 147456 B
    int* deg   = (int*)(ws + 12877824);                               // 65536 B
    int* slots = (int*)(ws + 12943360);                               // 4194304 B

    // int64 edge_index -> in_sizes[1] = 2*E*8 = 4 MB; int32 -> 2 MB.
    bool is64 = (in_sizes[1] >= (int)(2u * Ecnt * 8u));

    hipMemsetAsync(deg, 0, BN * sizeof(int), stream);   // 64 KB, ~1 us
    if (is64)
        combo_kernel<1><<<3872, 256, 0, stream>>>(x, W, ew, xb, Wxa, Wa, deg, slots);
    else
        combo_kernel<0><<<3872, 256, 0, stream>>>(x, W, ew, xb, Wxa, Wa, deg, slots);
    p2_kernel<<<BN / 32, 512, 0, stream>>>(deg, slots, xb, Wxa, Wa, bias, out);
}

// Round 20
// 114.678 us; speedup vs baseline: 1.0587x; 1.0587x over previous
//
#include <hip/hip_runtime.h>
#include <hip/hip_bf16.h>
#include <math.h>

// Problem constants
#define Bz    4
#define Cch   192
#define Nn    4096
#define BN    16384      // Bz*Nn
#define Ecnt  262144     // Bz*Nn*16
#define COUT  384
#define CAP   64         // max degree capacity (random 262144->16384 bins: max ~34)

typedef __attribute__((ext_vector_type(8))) short short8;
typedef __attribute__((ext_vector_type(4))) float floatx4;

__device__ __forceinline__ void gload_lds16(const void* g, void* l) {
    __builtin_amdgcn_global_load_lds(
        (const __attribute__((address_space(1))) unsigned int*)g,
        (__attribute__((address_space(3))) unsigned int*)l, 16, 0, 0);
}

__device__ __forceinline__ float b2f(unsigned short u) {
    union { unsigned int i; float f; } z; z.i = ((unsigned int)u) << 16; return z.f;
}
__device__ __forceinline__ unsigned short f2b(float f) {
    __hip_bfloat16 h = __float2bfloat16(f);
    return *(unsigned short*)&h;
}

#define RED8(mm, FLD) do {                                                    \
    float a_ = fmaxf(fmaxf(b2f(v[0].FLD), b2f(v[1].FLD)),                     \
                     fmaxf(b2f(v[2].FLD), b2f(v[3].FLD)));                    \
    float b_ = fmaxf(fmaxf(b2f(v[4].FLD), b2f(v[5].FLD)),                     \
                     fmaxf(b2f(v[6].FLD), b2f(v[7].FLD)));                    \
    mm = fmaxf(mm, fmaxf(a_, b_)); } while (0)

#define RED16(mm, FLD) do {                                                   \
    float a_ = fmaxf(fmaxf(fmaxf(b2f(v[0].FLD), b2f(v[1].FLD)),               \
                           fmaxf(b2f(v[2].FLD), b2f(v[3].FLD))),              \
                     fmaxf(fmaxf(b2f(v[4].FLD), b2f(v[5].FLD)),               \
                           fmaxf(b2f(v[6].FLD), b2f(v[7].FLD))));             \
    float b_ = fmaxf(fmaxf(fmaxf(b2f(v[8].FLD), b2f(v[9].FLD)),               \
                           fmaxf(b2f(v[10].FLD), b2f(v[11].FLD))),            \
                     fmaxf(fmaxf(b2f(v[12].FLD), b2f(v[13].FLD)),             \
                           fmaxf(b2f(v[14].FLD), b2f(v[15].FLD))));           \
    mm = fmaxf(mm, fmaxf(a_, b_)); } while (0)

// ---------------------------------------------------------------------------
// Combo kernel (R18-measured): prep + fill in one dispatch; deg zeroed by a
// prior hipMemsetAsync.
//  [0,3072):    transpose x -> xb bf16 (R2-proven tile)
//  [3072,3360): W -> Wxa=bf16(Wx-Wa), Wa=bf16(Wa)
//  [3360,3872): fill — degree count + slot table, 2 edges/thread
// Algebra: out = Wx·x + Wa·(M-x) = (Wx-Wa)·x + Wa·M', M' = (d>0 ? max : x).
template <int IS64>
__global__ __launch_bounds__(256) void combo_kernel(
    const float* __restrict__ x, const float* __restrict__ W,
    const int* __restrict__ ew, __hip_bfloat16* __restrict__ xb,
    __hip_bfloat16* __restrict__ Wxa, __hip_bfloat16* __restrict__ Wa,
    int* __restrict__ deg, int* __restrict__ slots) {
    int bid = blockIdx.x;
    if (bid < 3072) {
        __shared__ float tile[32][33];
        int b = bid / 768;
        int r = bid - b * 768;
        int c0 = (r >> 7) * 32;         // 6 c-tiles
        int n0 = (r & 127) * 32;        // 128 n-tiles
        int tx = threadIdx.x & 31, ty = threadIdx.x >> 5;
        for (int i = ty; i < 32; i += 8)
            tile[i][tx] = x[((size_t)(b * Cch + c0 + i)) * Nn + n0 + tx];
        __syncthreads();
        for (int i = ty; i < 32; i += 8)
            xb[((size_t)(b * Nn + n0 + i)) * Cch + c0 + tx] =
                __float2bfloat16(tile[tx][i]);
    } else if (bid < 3360) {
        int i = (bid - 3072) * 256 + threadIdx.x;   // exactly COUT*Cch = 73728
        int o = i / Cch, c = i - o * Cch;
        float wx = W[o * 2 * Cch + 2 * c];
        float wa = W[o * 2 * Cch + 2 * c + 1];
        Wxa[i] = __float2bfloat16(wx - wa);          // fp32 difference, one rounding
        Wa[i]  = __float2bfloat16(wa);
    } else {
        int t = (bid - 3360) * 256 + threadIdx.x;   // [0, Ecnt/2), 2 edges/thread
        int d0, d1, s0, s1;
        if (IS64) {     // int64: dst e -> word 2e; src e -> word 2*Ecnt + 2e
            int4 dv = *(const int4*)&ew[4 * t];
            int4 sv = *(const int4*)&ew[2 * Ecnt + 4 * t];
            d0 = dv.x; d1 = dv.z; s0 = sv.x; s1 = sv.z;
        } else {        // int32
            int2 dv = *(const int2*)&ew[2 * t];
            int2 sv = *(const int2*)&ew[Ecnt + 2 * t];
            d0 = dv.x; d1 = dv.y; s0 = sv.x; s1 = sv.y;
        }
        int p0 = atomicAdd(&deg[d0], 1); if (p0 < CAP) slots[(d0 << 6) + p0] = s0;
        int p1 = atomicAdd(&deg[d1], 1); if (p1 < CAP) slots[(d1 << 6) + p1] = s1;
    }
}

// ---------------------------------------------------------------------------
// Agg: Mb[node][c] = (d>0) ? max_{s in N(node)} xb[s][c] : xb[node][c]
// R2's champion shape (1 node/wave, 16384 waves = max TLP, one latency chain
// per wave) + R17's mechanism (unconditional slots load; 16-deep batches —
// one batch covers the mean degree).
__global__ __launch_bounds__(256) void agg_kernel(
    const int* __restrict__ deg, const int* __restrict__ slots,
    const __hip_bfloat16* __restrict__ xb, __hip_bfloat16* __restrict__ Mb) {
    int lane = threadIdx.x & 63, wave = threadIdx.x >> 6;
    int node = (blockIdx.x << 2) + wave;
    int d = deg[node];                                 // chain 1
    int nbrval = slots[(node << 6) + lane];            // chain 2 (parallel)
    const unsigned short* xbu = (const unsigned short*)xb;
    int act = lane < 48;
    int cb = lane * 4;
    ushort4 xv = {0, 0, 0, 0};
    if (act) xv = *(const ushort4*)&xbu[node * Cch + cb];  // chain 3 (parallel)
    if (d > CAP) d = CAP;
    d = __builtin_amdgcn_readfirstlane(d);             // wave-uniform bound
    float m0 = -INFINITY, m1 = -INFINITY, m2 = -INFINITY, m3 = -INFINITY;
    int k = 0;
    for (; k + 16 <= d; k += 16) {
        int s[16];
#pragma unroll
        for (int u = 0; u < 16; u++) s[u] = __builtin_amdgcn_readlane(nbrval, k + u);
        if (act) {
            ushort4 v[16];
#pragma unroll
            for (int u = 0; u < 16; u++) v[u] = *(const ushort4*)&xbu[s[u] * Cch + cb];
            RED16(m0, x); RED16(m1, y); RED16(m2, z); RED16(m3, w);
        }
    }
    for (; k + 8 <= d; k += 8) {
        int s[8];
#pragma unroll
        for (int u = 0; u < 8; u++) s[u] = __builtin_amdgcn_readlane(nbrval, k + u);
        if (act) {
            ushort4 v[8];
#pragma unroll
            for (int u = 0; u < 8; u++) v[u] = *(const ushort4*)&xbu[s[u] * Cch + cb];
            RED8(m0, x); RED8(m1, y); RED8(m2, z); RED8(m3, w);
        }
    }
    for (; k < d; k++) {
        int s = __builtin_amdgcn_readlane(nbrval, k);
        if (act) {
            ushort4 v = *(const ushort4*)&xbu[s * Cch + cb];
            m0 = fmaxf(m0, b2f(v.x)); m1 = fmaxf(m1, b2f(v.y));
            m2 = fmaxf(m2, b2f(v.z)); m3 = fmaxf(m3, b2f(v.w));
        }
    }
    if (act) {
        ushort4 o4;
        if (d > 0) {                         // wave-uniform branch
            o4.x = f2b(m0); o4.y = f2b(m1); o4.z = f2b(m2); o4.w = f2b(m3);
        } else {                             // empty segment: M' = x (cancels)
            o4 = xv;
        }
        *(ushort4*)&((unsigned short*)Mb)[node * Cch + cb] = o4;
    }
}

// ---------------------------------------------------------------------------
// GEMM (R2-measured verbatim): out[b][o][n] = relu(Wxa·xb + Wa·Mb + bias).
// 64(node) x 128(o) tile; grid (256,3); 4 waves. Double-buffered LDS,
// 1 barrier per 32-k step (12 total). Steps 0..5: (Xb,Wxa); 6..11: (Mb,Wa).
__global__ __launch_bounds__(256) void gemm_kernel(
    const __hip_bfloat16* __restrict__ Xb, const __hip_bfloat16* __restrict__ Ab,
    const __hip_bfloat16* __restrict__ Wxa, const __hip_bfloat16* __restrict__ Wa,
    const float* __restrict__ bias, float* __restrict__ out) {
    __shared__ short As[2][64 * 32];    // 2 x 4 KB  [node][k]
    __shared__ short Bs[2][128 * 32];   // 2 x 8 KB  [o][k]
    int t = threadIdx.x;
    int node0 = blockIdx.x * 64;
    int o0    = blockIdx.y * 128;
    int lane = t & 63, wave = t >> 6;
    int quad = lane >> 4, lrow = lane & 15;
    int wm = wave & 1, wn = wave >> 1;

    floatx4 acc[2][4] = {};
    int srow = t >> 2;             // 0..63 (4 threads per row)
    int koff = (t & 3) * 8;        // 0,8,16,24 elements within 32-k tile

    size_t aoff = (size_t)(node0 + srow) * Cch + koff;
    size_t boff = (size_t)(o0 + srow) * Cch + koff;
    const __hip_bfloat16* Ag[2] = {Xb + aoff, Ab + aoff};
    const __hip_bfloat16* Bg[2] = {Wxa + boff, Wa + boff};

    auto STAGE = [&](int s, int b) {
        int seg = (s >= 6);
        int kt = (seg ? s - 6 : s) * 32;
        gload_lds16(Ag[seg] + kt, &As[b][t * 8]);
        gload_lds16(Bg[seg] + kt, &Bs[b][t * 8]);
        gload_lds16(Bg[seg] + (size_t)64 * Cch + kt, &Bs[b][2048 + t * 8]);
    };

    STAGE(0, 0);
    __syncthreads();               // drains vmcnt(0): buf0 ready
    for (int s = 0; s < 12; s++) {
        int p = s & 1;
        if (s < 11) STAGE(s + 1, p ^ 1);   // prefetch next tile into other buf
        short8 af[2], bf[4];
#pragma unroll
        for (int i = 0; i < 2; i++)
            af[i] = *(const short8*)&As[p][(wm * 32 + i * 16 + lrow) * 32 + quad * 8];
#pragma unroll
        for (int j = 0; j < 4; j++)
            bf[j] = *(const short8*)&Bs[p][(wn * 64 + j * 16 + lrow) * 32 + quad * 8];
#pragma unroll
        for (int i = 0; i < 2; i++)
#pragma unroll
            for (int j = 0; j < 4; j++)
                acc[i][j] = __builtin_amdgcn_mfma_f32_16x16x32_bf16(bf[j], af[i], acc[i][j], 0, 0, 0);
        __syncthreads();           // publish prefetched buf (vmcnt+lgkm drain)
    }

    // D layout: col(lane&15)=node, row(quad*4+r)=o
#pragma unroll
    for (int i = 0; i < 2; i++) {
        int node = node0 + wm * 32 + i * 16 + lrow;
        int b = node >> 12, n = node & 4095;
#pragma unroll
        for (int j = 0; j < 4; j++) {
            int ob = o0 + wn * 64 + j * 16 + quad * 4;
#pragma unroll
            for (int r = 0; r < 4; r++) {
                int o = ob + r;
                float v = acc[i][j][r] + bias[o];
                out[((size_t)(b * COUT + o)) * Nn + n] = fmaxf(v, 0.0f);
            }
        }
    }
}

// ---------------------------------------------------------------------------
extern "C" void kernel_launch(void* const* d_in, const int* in_sizes, int n_in,
                              void* d_out, int out_size, void* d_ws, size_t ws_size,
                              hipStream_t stream) {
    const float* x    = (const float*)d_in[0];
    const int*   ew   = (const int*)d_in[1];
    const float* W    = (const float*)d_in[2];
    const float* bias = (const float*)d_in[3];
    float* out        = (float*)d_out;

    char* ws = (char*)d_ws;
    __hip_bfloat16* xb   = (__hip_bfloat16*)ws;                       // 6291456 B
    __hip_bfloat16* Mb   = (__hip_bfloat16*)(ws + 6291456);           // 6291456 B
    __hip_bfloat16* Wxa  = (__hip_bfloat16*)(ws + 12582912);          // 147456 B
    __hip_bfloat16* Wa   = (__hip_bfloat16*)(ws + 12730368);          // 147456 B
    int* deg   = (int*)(ws + 12877824);                               // 65536 B
    int* slots = (int*)(ws + 12943360);                               // 4194304 B

    // int64 edge_index -> in_sizes[1] = 2*E*8 = 4 MB; int32 -> 2 MB.
    bool is64 = (in_sizes[1] >= (int)(2u * Ecnt * 8u));

    hipMemsetAsync(deg, 0, BN * sizeof(int), stream);   // 64 KB, ~1 us
    if (is64)
        combo_kernel<1><<<3872, 256, 0, stream>>>(x, W, ew, xb, Wxa, Wa, deg, slots);
    else
        combo_kernel<0><<<3872, 256, 0, stream>>>(x, W, ew, xb, Wxa, Wa, deg, slots);
    agg_kernel<<<BN / 4, 256, 0, stream>>>(deg, slots, xb, Mb);
    gemm_kernel<<<dim3(BN / 64, COUT / 128), 256, 0, stream>>>(xb, Mb, Wxa, Wa, bias, out);
}